// Round 2
// baseline (4655.089 us; speedup 1.0000x reference)
//
#include <hip/hip_runtime.h>

typedef unsigned short u16;
typedef unsigned int   u32;

#define B_    128
#define N_    8192
#define HD_   256
#define X_    768          // 3*HD
#define T_    10
#define SEGS_ 16
#define SEGROWS_ 512       // N_/SEGS_

// ---- persistent per-call state in device globals (no d_ws dependence) ----
__device__ float g_h[B_*HD_];
__device__ float g_c[B_*HD_];
__device__ float g_q[B_*HD_];
__device__ float g_pval[B_*SEGS_*3];
__device__ int   g_pidx[B_*SEGS_*3];
__device__ int   g_isf32;

__device__ __forceinline__ float bf2f(u16 u){ return __uint_as_float(((u32)u)<<16); }
__device__ __forceinline__ float lo2f(u32 w){ return __uint_as_float(w<<16); }
__device__ __forceinline__ float hi2f(u32 w){ return __uint_as_float(w & 0xffff0000u); }
__device__ __forceinline__ u16 f2bf(float f){
  u32 u = __float_as_uint(f);
  u32 r = u + 0x7fffu + ((u>>16)&1u);   // RNE
  return (u16)(r>>16);
}

template<bool F32>
__device__ __forceinline__ float ld1(const void* p, size_t i){
  if constexpr (F32) return ((const float*)p)[i];
  else               return bf2f(((const u16*)p)[i]);
}

template<bool F32>
__device__ __forceinline__ void st1(void* p, size_t i, float v){
  if constexpr (F32) ((float*)p)[i] = v;
  else               ((u16*)p)[i]   = f2bf(v);
}

template<bool F32>
__device__ __forceinline__ void ld8(const void* p, size_t i, float* o){
  if constexpr (F32){
    const float4* q = (const float4*)((const float*)p + i);
    float4 a = q[0], b = q[1];
    o[0]=a.x; o[1]=a.y; o[2]=a.z; o[3]=a.w;
    o[4]=b.x; o[5]=b.y; o[6]=b.z; o[7]=b.w;
  } else {
    uint4 u = *(const uint4*)((const u16*)p + i);
    o[0]=lo2f(u.x); o[1]=hi2f(u.x); o[2]=lo2f(u.y); o[3]=hi2f(u.y);
    o[4]=lo2f(u.z); o[5]=hi2f(u.z); o[6]=lo2f(u.w); o[7]=hi2f(u.w);
  }
}

// top-3 insert, jax.lax.top_k tie-break (equal value -> lower index first)
__device__ __forceinline__ void t3ins(float v,int i,
    float&v0,int&i0,float&v1,int&i1,float&v2,int&i2){
  if (v>v0 || (v==v0 && i<i0)) { v2=v1;i2=i1; v1=v0;i1=i0; v0=v;i0=i; }
  else if (v>v1 || (v==v1 && i<i1)) { v2=v1;i2=i1; v1=v;i1=i; }
  else if (v>v2 || (v==v2 && i<i2)) { v2=v;i2=i; }
}

// ---- dtype probe ----
__global__ void k_probe(const void* enc){
  const int lane = threadIdx.x;           // 64 threads
  const u16 u = ((const u16*)enc)[lane*2];
  const float a = fabsf(bf2f(u));
  const bool inr = (a >= 0.0009765625f) && (a <= 1024.0f);
  unsigned long long m = __ballot(inr ? 1 : 0);
  if (lane==0) g_isf32 = (__popcll(m) < 32) ? 1 : 0;
}

// ---- K1: merge prev partials -> idx output + gather x, LSTM, query ----
template<bool F32>
__device__ void lstm_body(const void* enc, const void* h0, const void* c0,
  const void* x0, const void* Wih, const void* bih, const void* Whh,
  const void* bhh, const void* Wq, const void* bq, void* out, int t)
{
  const int b = blockIdx.x, d = threadIdx.x;
  __shared__ float xs[X_];
  __shared__ float hs[HD_];
  __shared__ float hn[HD_];
  __shared__ int   idx3[3];

  float cd;
  if (t == 0){
    for (int i=d;i<X_;i+=256) xs[i] = ld1<F32>(x0, (size_t)b*X_+i);
    hs[d] = ld1<F32>(h0, (size_t)b*HD_+d);
    cd    = ld1<F32>(c0, (size_t)b*HD_+d);
  } else {
    if (d==0){
      float v0=-3.4e38f,v1=-3.4e38f,v2=-3.4e38f; int i0=-1,i1=-1,i2=-1;
      const float* pv = g_pval + b*SEGS_*3;
      const int*   pi = g_pidx + b*SEGS_*3;
      for (int s=0;s<SEGS_*3;s++) t3ins(pv[s],pi[s],v0,i0,v1,i1,v2,i2);
      idx3[0]=i0; idx3[1]=i1; idx3[2]=i2;
      const size_t ib = (size_t)T_*B_*N_ + (size_t)(t-1)*B_*3 + (size_t)b*3;
      st1<F32>(out, ib+0, (float)i0);
      st1<F32>(out, ib+1, (float)i1);
      st1<F32>(out, ib+2, (float)i2);
    }
    __syncthreads();
    #pragma unroll
    for (int j=0;j<3;j++){
      int jj = idx3[j]; jj = jj<0 ? 0 : (jj>N_-1 ? N_-1 : jj);   // crash guard
      xs[j*HD_+d] = ld1<F32>(enc, ((size_t)b*N_ + jj)*HD_ + d);
    }
    hs[d] = g_h[b*HD_+d];
    cd    = g_c[b*HD_+d];
  }
  __syncthreads();

  float g4[4];
  #pragma unroll
  for (int gi=0;gi<4;gi++){
    const int row = gi*HD_ + d;
    float acc = ld1<F32>(bih,row) + ld1<F32>(bhh,row);
    #pragma unroll 4
    for (int kk=0;kk<X_/8;kk++){
      float w[8]; ld8<F32>(Wih, (size_t)row*X_ + kk*8, w);
      #pragma unroll
      for (int j=0;j<8;j++) acc = fmaf(xs[kk*8+j], w[j], acc);
    }
    #pragma unroll 4
    for (int kk=0;kk<HD_/8;kk++){
      float w[8]; ld8<F32>(Whh, (size_t)row*HD_ + kk*8, w);
      #pragma unroll
      for (int j=0;j<8;j++) acc = fmaf(hs[kk*8+j], w[j], acc);
    }
    g4[gi]=acc;
  }
  const float sig_i = 1.f/(1.f+expf(-g4[0]));
  const float sig_f = 1.f/(1.f+expf(-g4[1]));
  const float tan_g = tanhf(g4[2]);
  const float sig_o = 1.f/(1.f+expf(-g4[3]));
  const float cn = sig_f*cd + sig_i*tan_g;
  const float hv = sig_o*tanhf(cn);
  g_c[b*HD_+d]=cn; g_h[b*HD_+d]=hv; hn[d]=hv;
  __syncthreads();

  float acc = ld1<F32>(bq,d);
  #pragma unroll 4
  for (int kk=0;kk<HD_/8;kk++){
    float w[8]; ld8<F32>(Wq, (size_t)d*HD_ + kk*8, w);
    #pragma unroll
    for (int j=0;j<8;j++) acc = fmaf(hn[kk*8+j], w[j], acc);
  }
  g_q[b*HD_+d]=acc;
}

__global__ __launch_bounds__(256) void k_lstm(
  const void* enc, const void* h0, const void* c0, const void* x0,
  const void* Wih, const void* bih, const void* Whh, const void* bhh,
  const void* Wq, const void* bq, void* out, int t)
{
  if (g_isf32) lstm_body<true >(enc,h0,c0,x0,Wih,bih,Whh,bhh,Wq,bq,out,t);
  else         lstm_body<false>(enc,h0,c0,x0,Wih,bih,Whh,bhh,Wq,bq,out,t);
}

// ---- K2: logits + per-segment partial top-3 ----
template<bool F32>
__device__ void logits_body(const void* enc, void* out, int t)
{
  const int seg = blockIdx.x, b = blockIdx.y;
  const int tid  = threadIdx.x;
  const int wave = tid>>6;
  const int lane = tid&63;
  const int kl   = lane&31;
  const int half = lane>>5;

  float qv[8];
  const float* qb = g_q + b*HD_ + kl*8;
  #pragma unroll
  for (int j=0;j<8;j++) qv[j]=qb[j];

  float v0=-3.4e38f,v1=-3.4e38f,v2=-3.4e38f; int i0=-1,i1=-1,i2=-1;
  const size_t rowbase = (size_t)b*N_ + seg*SEGROWS_;
  const size_t obase   = (size_t)t*B_*N_ + rowbase;

  #pragma unroll 2
  for (int it=0; it<SEGROWS_/8; ++it){   // 64 iters: 4 waves x 2 halves
    const int n = (it*4 + wave)*2 + half;
    float w[8]; ld8<F32>(enc, (rowbase + n)*HD_ + kl*8, w);
    float acc =       qv[0]*w[0];
    acc = fmaf(qv[1], w[1], acc);
    acc = fmaf(qv[2], w[2], acc);
    acc = fmaf(qv[3], w[3], acc);
    acc = fmaf(qv[4], w[4], acc);
    acc = fmaf(qv[5], w[5], acc);
    acc = fmaf(qv[6], w[6], acc);
    acc = fmaf(qv[7], w[7], acc);
    #pragma unroll
    for (int off=16; off>=1; off>>=1)
      acc += __shfl_xor(acc, off, 64);   // stays within each 32-lane half
    if (kl==0) st1<F32>(out, obase + n, acc);
    t3ins(acc, seg*SEGROWS_+n, v0,i0,v1,i1,v2,i2);
  }

  __shared__ float sv[8][3];
  __shared__ int   si[8][3];
  if (kl==0){
    const int slot = wave*2+half;
    sv[slot][0]=v0; sv[slot][1]=v1; sv[slot][2]=v2;
    si[slot][0]=i0; si[slot][1]=i1; si[slot][2]=i2;
  }
  __syncthreads();
  if (tid==0){
    float w0=-3.4e38f,w1=-3.4e38f,w2=-3.4e38f; int j0=-1,j1=-1,j2=-1;
    for (int s=0;s<8;s++)
      for (int k=0;k<3;k++)
        t3ins(sv[s][k],si[s][k],w0,j0,w1,j1,w2,j2);
    float* pv = g_pval + (b*SEGS_+seg)*3;
    int*   pi = g_pidx + (b*SEGS_+seg)*3;
    pv[0]=w0; pv[1]=w1; pv[2]=w2;
    pi[0]=j0; pi[1]=j1; pi[2]=j2;
  }
}

__global__ __launch_bounds__(256) void k_logits(const void* enc, void* out, int t)
{
  if (g_isf32) logits_body<true >(enc,out,t);
  else         logits_body<false>(enc,out,t);
}

// ---- K3: final merge for the last step's indices ----
__global__ void k_final(void* out)
{
  const int b = blockIdx.x;
  if (threadIdx.x==0){
    float v0=-3.4e38f,v1=-3.4e38f,v2=-3.4e38f; int i0=-1,i1=-1,i2=-1;
    const float* pv = g_pval + b*SEGS_*3;
    const int*   pi = g_pidx + b*SEGS_*3;
    for (int s=0;s<SEGS_*3;s++) t3ins(pv[s],pi[s],v0,i0,v1,i1,v2,i2);
    const size_t ib = (size_t)T_*B_*N_ + (size_t)(T_-1)*B_*3 + (size_t)b*3;
    if (g_isf32){
      ((float*)out)[ib+0]=(float)i0;
      ((float*)out)[ib+1]=(float)i1;
      ((float*)out)[ib+2]=(float)i2;
    } else {
      ((u16*)out)[ib+0]=f2bf((float)i0);
      ((u16*)out)[ib+1]=f2bf((float)i1);
      ((u16*)out)[ib+2]=f2bf((float)i2);
    }
  }
}

extern "C" void kernel_launch(void* const* d_in, const int* in_sizes, int n_in,
                              void* d_out, int out_size, void* d_ws, size_t ws_size,
                              hipStream_t stream)
{
  (void)in_sizes; (void)n_in; (void)out_size; (void)d_ws; (void)ws_size;
  const void* enc = d_in[0];
  const void* h0  = d_in[1];
  const void* c0  = d_in[2];
  // d_in[3] end_node_embed: unused in prediction mode
  const void* x0  = d_in[4];
  const void* Wih = d_in[5];
  const void* bih = d_in[6];
  const void* Whh = d_in[7];
  const void* bhh = d_in[8];
  const void* Wq  = d_in[9];
  const void* bq  = d_in[10];
  // d_in[11] max_steps == 10 (fixed by setup_inputs)

  k_probe<<<dim3(1),dim3(64),0,stream>>>(enc);

  for (int t=0;t<T_;t++){
    k_lstm<<<dim3(B_),dim3(256),0,stream>>>(enc,h0,c0,x0,Wih,bih,Whh,bhh,Wq,bq,
                                            d_out, t);
    k_logits<<<dim3(SEGS_,B_),dim3(256),0,stream>>>(enc, d_out, t);
  }
  k_final<<<dim3(B_),dim3(64),0,stream>>>(d_out);
}